// Round 3
// baseline (456.944 us; speedup 1.0000x reference)
//
#include <hip/hip_runtime.h>
#include <stdint.h>

typedef unsigned int u32;
typedef unsigned long long u64;

#define BB 16
#define SS 2048
#define MM 128
#define CC 32
#define DD 512
#define TT (SS + MM + CC)   // 2208
#define KSEL 17             // knn + 1 (self included)

// ws layout (bytes)
#define OFF_COLKEY 0
#define OFF_MIDTGT (128 << 10)
#define OFF_COATGT (256 << 10)
#define OFF_VPOS   (384 << 10)
#define OFF_VLEN   (512 << 10)
#define OFF_VCOORD (520 << 10)
#define OFF_KNN    (776 << 10)
#define KNN_BYTES  ((size_t)BB * SS * 64 * 4)      // 8 MiB
#define OFF_PROJ   ((size_t)(776 << 10) + KNN_BYTES)
#define PROJ_BYTES ((size_t)BB * MM * DD * 4)      // 4 MiB

typedef float nfloat4 __attribute__((ext_vector_type(4)));
__device__ __forceinline__ void st_nt_f4(float* p, float4 v) {
    nfloat4 nv; nv.x = v.x; nv.y = v.y; nv.z = v.z; nv.w = v.w;
    __builtin_nontemporal_store(nv, (nfloat4*)p);
}

// ---------------------------------------------------------------------------
// zero_kernel: zero the knnbits bitmask (replaces hipMemsetAsync — a memset
// node captured in the graph ran at 24 GB/s / 350 us; a plain kernel doesn't).
// grid 2048 x 256 x uint4 = exactly 8 MiB.
// ---------------------------------------------------------------------------
__global__ __launch_bounds__(256) void zero_kernel(uint4* __restrict__ p)
{
    const int tid = blockIdx.x * 256 + threadIdx.x;
    p[tid] = make_uint4(0u, 0u, 0u, 0u);
}

// ---------------------------------------------------------------------------
// prep: per-batch rank scan, packed column keys, mid/coarse targets, and the
// compacted valid-point arrays for knn (vpos[rank]=pos, vcoord[rank], vlen).
// colkey = valid<<31 | tok<<11 | rank.
// ---------------------------------------------------------------------------
__global__ __launch_bounds__(256) void prep_kernel(
    const float* __restrict__ coords,
    const int* __restrict__ step_mask, const int* __restrict__ tokens,
    const int* __restrict__ s2m, const int* __restrict__ mid_mask,
    const int* __restrict__ s2c, const int* __restrict__ coarse_mask,
    u32* __restrict__ colkey, int* __restrict__ midtgt, int* __restrict__ coatgt,
    u32* __restrict__ vpos, int* __restrict__ vlen, float2* __restrict__ vcoord)
{
    const int b = blockIdx.x, t = threadIdx.x;
    __shared__ int sums[256];
    const int base = b * SS + t * 8;
    int v[8]; int loc = 0;
#pragma unroll
    for (int e = 0; e < 8; ++e) { v[e] = step_mask[base + e] > 0; loc += v[e]; }
    sums[t] = loc;
    __syncthreads();
    int x = loc;
    for (int off = 1; off < 256; off <<= 1) {
        int y = (t >= off) ? sums[t - off] : 0;
        __syncthreads();
        x += y; sums[t] = x;
        __syncthreads();
    }
    if (t == 255) vlen[b] = x;     // total valid count
    int run = x - loc;             // exclusive prefix of valid counts
    const float2* cb = (const float2*)coords + (size_t)b * SS;
#pragma unroll
    for (int e = 0; e < 8; ++e) {
        const int idx = base + e;
        const int pos = t * 8 + e;
        run += v[e];
        u32 key = 0u;
        if (v[e]) {
            int rank = run - 1;
            key = 0x80000000u | ((u32)tokens[idx] << 11) | (u32)(rank & 0x7FF);
            vpos[b * SS + rank] = (u32)pos;
            vcoord[b * SS + rank] = cb[pos];
        }
        colkey[idx] = key;
        int sm = s2m[idx];
        midtgt[idx] = (v[e] && sm >= 0 && sm < MM && mid_mask[b * MM + sm] > 0) ? sm : -1;
        int sc = s2c[idx];
        coatgt[idx] = (v[e] && sc >= 0 && sc < CC && coarse_mask[b * CC + sc] > 0) ? sc : -1;
    }
}

// ---------------------------------------------------------------------------
// KNN: one wave per (b, i) valid row, scanning only the ~vlen compacted valid
// candidates. Each lane holds up to 32 slots packed as
//   (d2_bits << 22) | (rank << 11) | pos        (consumed slots -> ~0ull)
// (d2, rank) lexicographic == reference (d2, position) tie-break since rank is
// monotone in position. 17 rounds of {lane min-scan, 64-lane butterfly min,
// winner invalidation}. d2 replicates the reference float path exactly.
// ---------------------------------------------------------------------------
__global__ __launch_bounds__(256) void knn_kernel(
    const float* __restrict__ coords, const u32* __restrict__ colkey,
    const u32* __restrict__ vpos, const int* __restrict__ vlen,
    const float2* __restrict__ vcoord, u32* __restrict__ knnbits)
{
    const int wave = (blockIdx.x << 2) | (threadIdx.x >> 6);
    const int lane = threadIdx.x & 63;
    const int b = wave >> 11;
    const int i = wave & 2047;
    const u32 key_i = colkey[b * SS + i];
    if (!(key_i & 0x80000000u)) return;  // invalid row -> no knn edges

    const int n = vlen[b];
    const float2* cb = (const float2*)coords + (size_t)b * SS;
    const float2 ci = cb[i];
    const float sqi = __fadd_rn(__fmul_rn(ci.x, ci.x), __fmul_rn(ci.y, ci.y));

    u64 packed[32];
#pragma unroll
    for (int s = 0; s < 32; ++s) {
        packed[s] = ~0ull;
        if ((s << 6) < n) {
            const int r = (s << 6) | lane;
            if (r < n) {
                const float2 cj = vcoord[(b << 11) + r];
                const u32 pos = vpos[(b << 11) + r];
                const float sqj = __fadd_rn(__fmul_rn(cj.x, cj.x), __fmul_rn(cj.y, cj.y));
                const float dot = __builtin_fmaf(ci.y, cj.y, __fmul_rn(ci.x, cj.x));
                float d2 = __fsub_rn(__fadd_rn(sqi, sqj), __fmul_rn(2.0f, dot));
                d2 = fmaxf(d2, 0.0f);
                packed[s] = ((u64)__float_as_uint(d2) << 22) | ((u32)r << 11) | pos;
            }
        }
    }

    u32* rowi = knnbits + ((size_t)((b << 11) | i) << 6);
    for (int rnd = 0; rnd < KSEL; ++rnd) {
        u64 best = ~0ull;
#pragma unroll
        for (int s = 0; s < 32; ++s) {
            if ((s << 6) < n) best = (packed[s] < best) ? packed[s] : best;
        }
#pragma unroll
        for (int m = 1; m < 64; m <<= 1) {
            const u64 o = __shfl_xor(best, m, 64);
            best = (o < best) ? o : best;
        }
        if (best == ~0ull) break;  // fewer than 17 valid candidates
        const u32 lo = (u32)best;
        const u32 wrank = (lo >> 11) & 0x7FFu;
        const u32 wposn = lo & 0x7FFu;
        // invalidate the winner slot (exactly one lane, one slot)
#pragma unroll
        for (int s = 0; s < 32; ++s) {
            if ((s << 6) < n) {
                if (wrank == (u32)((s << 6) | lane)) packed[s] = ~0ull;
            }
        }
        if (lane == 0) {
            atomicOr(&rowi[wposn >> 5], 1u << (wposn & 31));
            atomicOr(&knnbits[((size_t)((b << 11) | wposn) << 6) + (i >> 5)],
                     1u << (i & 31));
        }
    }
}

// ---------------------------------------------------------------------------
// graph writer: float4 per thread. graph[i][j] = v_i & v_j &
//   (i==j | |rank_i-rank_j|<=2 | tok_i==tok_j | knnbit)
// ---------------------------------------------------------------------------
__device__ __forceinline__ float graph_elem(u32 key_i, int ri, u32 kj, u32 knnw,
                                            int i, int j)
{
    if (!(kj & 0x80000000u)) return 0.0f;
    int rj = (int)(kj & 0x7FFu);
    int dr = ri - rj; dr = dr < 0 ? -dr : dr;
    const bool same = ((key_i ^ kj) & 0x1FF800u) == 0u;
    const bool knn = (knnw >> (j & 31)) & 1u;
    return (dr <= 2 || same || knn || (i == j)) ? 1.0f : 0.0f;
}

__global__ __launch_bounds__(256) void graph_kernel(
    const u32* __restrict__ colkey, const u32* __restrict__ knnbits,
    float* __restrict__ out)
{
    const int tid = blockIdx.x * 256 + threadIdx.x;   // b*2^20 + i*512 + j4
    const int j4 = tid & 511;
    const int i = (tid >> 9) & 2047;
    const int b = tid >> 20;
    const int jb = j4 << 2;
    const u32 key_i = colkey[(b << 11) | i];
    float4 o;
    if (!(key_i & 0x80000000u)) {
        o = make_float4(0.f, 0.f, 0.f, 0.f);
    } else {
        const uint4 kj = *(const uint4*)(colkey + (b << 11) + jb);
        const u32 knnw = knnbits[(((size_t)((b << 11) | i)) << 6) + (jb >> 5)];
        const int ri = (int)(key_i & 0x7FFu);
        o.x = graph_elem(key_i, ri, kj.x, knnw, i, jb);
        o.y = graph_elem(key_i, ri, kj.y, knnw, i, jb + 1);
        o.z = graph_elem(key_i, ri, kj.z, knnw, i, jb + 2);
        o.w = graph_elem(key_i, ri, kj.w, knnw, i, jb + 3);
    }
    st_nt_f4(out + ((size_t)tid << 2), o);
}

// ---------------------------------------------------------------------------
// attn writer: float4 per thread over [T,T]; T=2208, 552 quads per row.
// Region boundaries (2048, 2176) are multiples of 4 -> per-thread uniform.
// ---------------------------------------------------------------------------
__global__ __launch_bounds__(256) void attn_kernel(
    const u32* __restrict__ colkey, const int* __restrict__ midtgt,
    const int* __restrict__ coatgt, float* __restrict__ out)
{
    const int tid = blockIdx.x * 256 + threadIdx.x;
    const int c4 = tid % 552;
    const int rt = tid / 552;   // b*T + r
    const int r = rt % TT;
    const int b = rt / TT;
    const int cb = c4 << 2;
    float4 o;
    if (r < SS) {
        if (cb < SS) {
            const u32 vr = colkey[b * SS + r] >> 31;
            const uint4 kc = *(const uint4*)(colkey + b * SS + cb);
            o.x = ((vr & (kc.x >> 31)) | (u32)(r == cb))     ? 1.f : 0.f;
            o.y = ((vr & (kc.y >> 31)) | (u32)(r == cb + 1)) ? 1.f : 0.f;
            o.z = ((vr & (kc.z >> 31)) | (u32)(r == cb + 2)) ? 1.f : 0.f;
            o.w = ((vr & (kc.w >> 31)) | (u32)(r == cb + 3)) ? 1.f : 0.f;
        } else if (cb < SS + MM) {
            const int mt = midtgt[b * SS + r];
            const int m0 = cb - SS;
            o.x = (mt == m0)     ? 1.f : 0.f;
            o.y = (mt == m0 + 1) ? 1.f : 0.f;
            o.z = (mt == m0 + 2) ? 1.f : 0.f;
            o.w = (mt == m0 + 3) ? 1.f : 0.f;
        } else {
            const int ct = coatgt[b * SS + r];
            const int c0 = cb - SS - MM;
            o.x = (ct == c0)     ? 1.f : 0.f;
            o.y = (ct == c0 + 1) ? 1.f : 0.f;
            o.z = (ct == c0 + 2) ? 1.f : 0.f;
            o.w = (ct == c0 + 3) ? 1.f : 0.f;
        }
    } else if (r < SS + MM) {
        const int m = r - SS;
        if (cb < SS) {
            const int4 mt = *(const int4*)(midtgt + b * SS + cb);
            o.x = (mt.x == m) ? 1.f : 0.f;
            o.y = (mt.y == m) ? 1.f : 0.f;
            o.z = (mt.z == m) ? 1.f : 0.f;
            o.w = (mt.w == m) ? 1.f : 0.f;
        } else {
            o.x = (cb == r)     ? 1.f : 0.f;
            o.y = (cb + 1 == r) ? 1.f : 0.f;
            o.z = (cb + 2 == r) ? 1.f : 0.f;
            o.w = (cb + 3 == r) ? 1.f : 0.f;
        }
    } else {
        const int cc = r - SS - MM;
        if (cb < SS) {
            const int4 ct = *(const int4*)(coatgt + b * SS + cb);
            o.x = (ct.x == cc) ? 1.f : 0.f;
            o.y = (ct.y == cc) ? 1.f : 0.f;
            o.z = (ct.z == cc) ? 1.f : 0.f;
            o.w = (ct.w == cc) ? 1.f : 0.f;
        } else {
            o.x = (cb == r)     ? 1.f : 0.f;
            o.y = (cb + 1 == r) ? 1.f : 0.f;
            o.z = (cb + 2 == r) ? 1.f : 0.f;
            o.w = (cb + 3 == r) ? 1.f : 0.f;
        }
    }
    st_nt_f4(out + (size_t)rt * TT + cb, o);
}

// ---------------------------------------------------------------------------
// fmaf-chain 4-wide dot helper (function, not a macro)
// ---------------------------------------------------------------------------
__device__ __forceinline__ float dot4(float acc, const float4& va, const float4& vb)
{
    return fmaf(va.x, vb.x, fmaf(va.y, vb.y, fmaf(va.z, vb.z, fmaf(va.w, vb.w, acc))));
}

// ---------------------------------------------------------------------------
// logits stage 1: proj[b,m,e] = sum_d mid[b,m,d] * W[e,d]
// ---------------------------------------------------------------------------
__global__ __launch_bounds__(256) void proj_kernel(
    const float* __restrict__ mid_hidden, const float* __restrict__ W,
    float* __restrict__ proj)
{
    const int b = blockIdx.z;
    const int m0 = blockIdx.y * 32 + (threadIdx.x >> 4) * 2;
    const int e0 = blockIdx.x * 64 + (threadIdx.x & 15) * 4;
    const float* a0 = mid_hidden + (size_t)(b * MM + m0) * DD;
    const float* a1 = a0 + DD;
    const float* w0 = W + (size_t)e0 * DD;
    const float* w1 = w0 + DD;
    const float* w2 = w1 + DD;
    const float* w3 = w2 + DD;
    float acc[2][4] = {};
    for (int k = 0; k < DD; k += 4) {
        const float4 va0 = *(const float4*)(a0 + k);
        const float4 va1 = *(const float4*)(a1 + k);
        const float4 vw0 = *(const float4*)(w0 + k);
        const float4 vw1 = *(const float4*)(w1 + k);
        const float4 vw2 = *(const float4*)(w2 + k);
        const float4 vw3 = *(const float4*)(w3 + k);
        acc[0][0] = dot4(acc[0][0], va0, vw0); acc[0][1] = dot4(acc[0][1], va0, vw1);
        acc[0][2] = dot4(acc[0][2], va0, vw2); acc[0][3] = dot4(acc[0][3], va0, vw3);
        acc[1][0] = dot4(acc[1][0], va1, vw0); acc[1][1] = dot4(acc[1][1], va1, vw1);
        acc[1][2] = dot4(acc[1][2], va1, vw2); acc[1][3] = dot4(acc[1][3], va1, vw3);
    }
    float* p0 = proj + (size_t)(b * MM + m0) * DD + e0;
    float* p1 = p0 + DD;
    p0[0] = acc[0][0]; p0[1] = acc[0][1]; p0[2] = acc[0][2]; p0[3] = acc[0][3];
    p1[0] = acc[1][0]; p1[1] = acc[1][1]; p1[2] = acc[1][2]; p1[3] = acc[1][3];
}

// ---------------------------------------------------------------------------
// logits stage 2: G[b,m,n] = (mm[m]&mm[n]) ? (proj[m]·proj[n]) / sqrt(D) : 0
// ---------------------------------------------------------------------------
__global__ __launch_bounds__(256) void logits_kernel(
    const float* __restrict__ proj, const int* __restrict__ mid_mask,
    float* __restrict__ out)
{
    const int b = blockIdx.z;
    const int m0 = blockIdx.y * 32 + (threadIdx.x >> 4) * 2;
    const int n0 = blockIdx.x * 32 + (threadIdx.x & 15) * 2;
    const float* pm0 = proj + (size_t)(b * MM + m0) * DD;
    const float* pm1 = pm0 + DD;
    const float* pn0 = proj + (size_t)(b * MM + n0) * DD;
    const float* pn1 = pn0 + DD;
    float acc[2][2] = {};
    for (int k = 0; k < DD; k += 4) {
        const float4 a0 = *(const float4*)(pm0 + k);
        const float4 a1 = *(const float4*)(pm1 + k);
        const float4 q0 = *(const float4*)(pn0 + k);
        const float4 q1 = *(const float4*)(pn1 + k);
        acc[0][0] = dot4(acc[0][0], a0, q0); acc[0][1] = dot4(acc[0][1], a0, q1);
        acc[1][0] = dot4(acc[1][0], a1, q0); acc[1][1] = dot4(acc[1][1], a1, q1);
    }
    const bool qm0 = mid_mask[b * MM + m0] > 0;
    const bool qm1 = mid_mask[b * MM + m0 + 1] > 0;
    const bool qn0 = mid_mask[b * MM + n0] > 0;
    const bool qn1 = mid_mask[b * MM + n0 + 1] > 0;
    const float sc = 22.62741699796952f;  // float32(sqrt(512)); ref divides
    float* o = out + (size_t)(b * MM + m0) * MM + n0;
    o[0]       = (qm0 && qn0) ? acc[0][0] / sc : 0.f;
    o[1]       = (qm0 && qn1) ? acc[0][1] / sc : 0.f;
    o[MM]      = (qm1 && qn0) ? acc[1][0] / sc : 0.f;
    o[MM + 1]  = (qm1 && qn1) ? acc[1][1] / sc : 0.f;
}

// ---------------------------------------------------------------------------
extern "C" void kernel_launch(void* const* d_in, const int* in_sizes, int n_in,
                              void* d_out, int out_size, void* d_ws, size_t ws_size,
                              hipStream_t stream)
{
    const float* coords      = (const float*)d_in[0];
    const int*   tokens      = (const int*)d_in[1];
    const int*   step_mask   = (const int*)d_in[2];
    const int*   s2m         = (const int*)d_in[3];
    const int*   mid_mask    = (const int*)d_in[4];
    const int*   s2c         = (const int*)d_in[5];
    const int*   coarse_mask = (const int*)d_in[6];
    const float* mid_hidden  = (const float*)d_in[7];
    const float* W_flow      = (const float*)d_in[8];

    float* graph_out  = (float*)d_out;
    float* attn_out   = graph_out + (size_t)BB * SS * SS;
    float* logits_out = attn_out + (size_t)BB * TT * TT;

    char* ws = (char*)d_ws;
    u32*    colkey  = (u32*)(ws + OFF_COLKEY);
    int*    midtgt  = (int*)(ws + OFF_MIDTGT);
    int*    coatgt  = (int*)(ws + OFF_COATGT);
    u32*    vpos    = (u32*)(ws + OFF_VPOS);
    int*    vlen    = (int*)(ws + OFF_VLEN);
    float2* vcoord  = (float2*)(ws + OFF_VCOORD);
    u32*    knnbits = (u32*)(ws + OFF_KNN);
    // If ws is tight, alias proj onto knnbits (safe: proj kernels run after
    // graph_kernel has consumed knnbits; stream order serializes).
    float* proj = (ws_size >= OFF_PROJ + PROJ_BYTES) ? (float*)(ws + OFF_PROJ)
                                                     : (float*)knnbits;

    zero_kernel<<<(int)(KNN_BYTES / (256 * 16)), 256, 0, stream>>>((uint4*)knnbits);
    prep_kernel<<<BB, 256, 0, stream>>>(coords, step_mask, tokens, s2m, mid_mask,
                                        s2c, coarse_mask, colkey, midtgt, coatgt,
                                        vpos, vlen, vcoord);
    knn_kernel<<<(BB * SS) / 4, 256, 0, stream>>>(coords, colkey, vpos, vlen,
                                                  vcoord, knnbits);
    graph_kernel<<<(BB * SS * (SS / 4)) / 256, 256, 0, stream>>>(colkey, knnbits, graph_out);
    attn_kernel<<<(BB * TT * (TT / 4)) / 256, 256, 0, stream>>>(colkey, midtgt, coatgt, attn_out);
    proj_kernel<<<dim3(DD / 64, MM / 32, BB), 256, 0, stream>>>(mid_hidden, W_flow, proj);
    logits_kernel<<<dim3(MM / 32, MM / 32, BB), 256, 0, stream>>>(proj, mid_mask, logits_out);
}

// Round 4
// 403.100 us; speedup vs baseline: 1.1336x; 1.1336x over previous
//
#include <hip/hip_runtime.h>
#include <stdint.h>

typedef unsigned int u32;
typedef unsigned long long u64;

#define BB 16
#define SS 2048
#define MM 128
#define CC 32
#define DD 512
#define TT (SS + MM + CC)   // 2208
#define KSEL 17             // knn + 1 (self included)

// ws layout (bytes)
#define OFF_COLKEY 0
#define OFF_MIDTGT (128 << 10)
#define OFF_COATGT (256 << 10)
#define OFF_KNN    (384 << 10)
#define KNN_BYTES  ((size_t)BB * SS * 64 * 4)      // 8 MiB
#define OFF_PROJ   ((size_t)(384 << 10) + KNN_BYTES)
#define PROJ_BYTES ((size_t)BB * MM * DD * 4)      // 4 MiB

// ---------------------------------------------------------------------------
// zero_kernel: zero the knnbits bitmask. 2048 blocks x 256 thr x 16B = 8 MiB.
// ---------------------------------------------------------------------------
__global__ __launch_bounds__(256) void zero_kernel(uint4* __restrict__ p)
{
    const int tid = blockIdx.x * 256 + threadIdx.x;
    p[tid] = make_uint4(0u, 0u, 0u, 0u);
}

// ---------------------------------------------------------------------------
// prep: per-batch rank (cumsum of valid - 1), packed column keys, mid/coarse
// targets. colkey = valid<<31 | tok<<11 | rank.
// ---------------------------------------------------------------------------
__global__ __launch_bounds__(256) void prep_kernel(
    const int* __restrict__ step_mask, const int* __restrict__ tokens,
    const int* __restrict__ s2m, const int* __restrict__ mid_mask,
    const int* __restrict__ s2c, const int* __restrict__ coarse_mask,
    u32* __restrict__ colkey, int* __restrict__ midtgt, int* __restrict__ coatgt)
{
    const int b = blockIdx.x, t = threadIdx.x;
    __shared__ int sums[256];
    const int base = b * SS + t * 8;
    int v[8]; int loc = 0;
#pragma unroll
    for (int e = 0; e < 8; ++e) { v[e] = step_mask[base + e] > 0; loc += v[e]; }
    sums[t] = loc;
    __syncthreads();
    int x = loc;
    for (int off = 1; off < 256; off <<= 1) {
        int y = (t >= off) ? sums[t - off] : 0;
        __syncthreads();
        x += y; sums[t] = x;
        __syncthreads();
    }
    int run = x - loc;  // exclusive prefix of valid counts
#pragma unroll
    for (int e = 0; e < 8; ++e) {
        const int idx = base + e;
        run += v[e];
        u32 key = 0u;
        if (v[e]) {
            int rank = run - 1;  // cumsum - 1
            key = 0x80000000u | ((u32)tokens[idx] << 11) | (u32)(rank & 0x7FF);
        }
        colkey[idx] = key;
        int sm = s2m[idx];
        midtgt[idx] = (v[e] && sm >= 0 && sm < MM && mid_mask[b * MM + sm] > 0) ? sm : -1;
        int sc = s2c[idx];
        coatgt[idx] = (v[e] && sc >= 0 && sc < CC && coarse_mask[b * CC + sc] > 0) ? sc : -1;
    }
}

// ---------------------------------------------------------------------------
// KNN: one wave per (b, i) row (round-2 proven version). Each lane holds 32
// candidates packed as (d2_bits << 32) | (j+1); invalid -> ~0. 17 rounds of
// min-over-{> prev} replicate lax.top_k tie-break (value asc, index asc).
// d2 replicates the reference float path exactly.
// ---------------------------------------------------------------------------
__global__ __launch_bounds__(256) void knn_kernel(
    const float* __restrict__ coords, const u32* __restrict__ colkey,
    u32* __restrict__ knnbits)
{
    const int wave = (blockIdx.x << 2) | (threadIdx.x >> 6);
    const int lane = threadIdx.x & 63;
    const int b = wave >> 11;
    const int i = wave & 2047;
    const u32 key_i = colkey[b * SS + i];
    if (!(key_i & 0x80000000u)) return;  // invalid row -> no knn edges

    const float2* cb = (const float2*)coords + (size_t)b * SS;
    const float2 ci = cb[i];
    const float sqi = __fadd_rn(__fmul_rn(ci.x, ci.x), __fmul_rn(ci.y, ci.y));

    u64 packed[32];
#pragma unroll
    for (int s = 0; s < 32; ++s) {
        const int j = (s << 6) | lane;
        const float2 cj = cb[j];
        const u32 kj = colkey[b * SS + j];
        const float sqj = __fadd_rn(__fmul_rn(cj.x, cj.x), __fmul_rn(cj.y, cj.y));
        const float dot = __builtin_fmaf(ci.y, cj.y, __fmul_rn(ci.x, cj.x));
        float d2 = __fsub_rn(__fadd_rn(sqi, sqj), __fmul_rn(2.0f, dot));
        d2 = fmaxf(d2, 0.0f);
        const u64 p = ((u64)__float_as_uint(d2) << 32) | (u32)(j + 1);
        packed[s] = (kj & 0x80000000u) ? p : ~0ull;
    }

    u64 prev = 0ull;
    u32* rowi = knnbits + ((size_t)(b * SS + i) << 6);
    for (int r = 0; r < KSEL; ++r) {
        u64 best = ~0ull;
#pragma unroll
        for (int s = 0; s < 32; ++s) {
            const u64 p = packed[s];
            const bool c = (p > prev) && (p < best);
            best = c ? p : best;
        }
#pragma unroll
        for (int m = 1; m < 64; m <<= 1) {
            const u64 o = __shfl_xor(best, m, 64);
            best = (o < best) ? o : best;
        }
        if (best == ~0ull) break;  // fewer than 17 valid candidates
        prev = best;
        if (lane == 0) {
            const u32 j = (u32)best - 1u;
            atomicOr(&rowi[j >> 5], 1u << (j & 31));
            atomicOr(&knnbits[((size_t)(b * SS + j) << 6) + (i >> 5)], 1u << (i & 31));
        }
    }
}

// ---------------------------------------------------------------------------
// graph writer: float4 per thread (cached stores — L3 write-back drains during
// the harness's next fill window; NT stores measurably cost +40 us).
// ---------------------------------------------------------------------------
__device__ __forceinline__ float graph_elem(u32 key_i, int ri, u32 kj, u32 knnw,
                                            int i, int j)
{
    if (!(kj & 0x80000000u)) return 0.0f;
    int rj = (int)(kj & 0x7FFu);
    int dr = ri - rj; dr = dr < 0 ? -dr : dr;
    const bool same = ((key_i ^ kj) & 0x1FF800u) == 0u;
    const bool knn = (knnw >> (j & 31)) & 1u;
    return (dr <= 2 || same || knn || (i == j)) ? 1.0f : 0.0f;
}

__global__ __launch_bounds__(256) void graph_kernel(
    const u32* __restrict__ colkey, const u32* __restrict__ knnbits,
    float* __restrict__ out)
{
    const int tid = blockIdx.x * 256 + threadIdx.x;   // b*2^20 + i*512 + j4
    const int j4 = tid & 511;
    const int i = (tid >> 9) & 2047;
    const int b = tid >> 20;
    const int jb = j4 << 2;
    const u32 key_i = colkey[(b << 11) | i];
    float4 o;
    if (!(key_i & 0x80000000u)) {
        o = make_float4(0.f, 0.f, 0.f, 0.f);
    } else {
        const uint4 kj = *(const uint4*)(colkey + (b << 11) + jb);
        const u32 knnw = knnbits[(((size_t)((b << 11) | i)) << 6) + (jb >> 5)];
        const int ri = (int)(key_i & 0x7FFu);
        o.x = graph_elem(key_i, ri, kj.x, knnw, i, jb);
        o.y = graph_elem(key_i, ri, kj.y, knnw, i, jb + 1);
        o.z = graph_elem(key_i, ri, kj.z, knnw, i, jb + 2);
        o.w = graph_elem(key_i, ri, kj.w, knnw, i, jb + 3);
    }
    *(float4*)(out + ((size_t)tid << 2)) = o;
}

// ---------------------------------------------------------------------------
// attn writer: float4 per thread over [T,T]; T=2208, 552 quads per row.
// No knnbits dependency -> scheduled BEFORE knn so its write-back drain
// overlaps knn's VALU-bound compute.
// ---------------------------------------------------------------------------
__global__ __launch_bounds__(256) void attn_kernel(
    const u32* __restrict__ colkey, const int* __restrict__ midtgt,
    const int* __restrict__ coatgt, float* __restrict__ out)
{
    const int tid = blockIdx.x * 256 + threadIdx.x;
    const int c4 = tid % 552;
    const int rt = tid / 552;   // b*T + r
    const int r = rt % TT;
    const int b = rt / TT;
    const int cb = c4 << 2;
    float4 o;
    if (r < SS) {
        if (cb < SS) {
            const u32 vr = colkey[b * SS + r] >> 31;
            const uint4 kc = *(const uint4*)(colkey + b * SS + cb);
            o.x = ((vr & (kc.x >> 31)) | (u32)(r == cb))     ? 1.f : 0.f;
            o.y = ((vr & (kc.y >> 31)) | (u32)(r == cb + 1)) ? 1.f : 0.f;
            o.z = ((vr & (kc.z >> 31)) | (u32)(r == cb + 2)) ? 1.f : 0.f;
            o.w = ((vr & (kc.w >> 31)) | (u32)(r == cb + 3)) ? 1.f : 0.f;
        } else if (cb < SS + MM) {
            const int mt = midtgt[b * SS + r];
            const int m0 = cb - SS;
            o.x = (mt == m0)     ? 1.f : 0.f;
            o.y = (mt == m0 + 1) ? 1.f : 0.f;
            o.z = (mt == m0 + 2) ? 1.f : 0.f;
            o.w = (mt == m0 + 3) ? 1.f : 0.f;
        } else {
            const int ct = coatgt[b * SS + r];
            const int c0 = cb - SS - MM;
            o.x = (ct == c0)     ? 1.f : 0.f;
            o.y = (ct == c0 + 1) ? 1.f : 0.f;
            o.z = (ct == c0 + 2) ? 1.f : 0.f;
            o.w = (ct == c0 + 3) ? 1.f : 0.f;
        }
    } else if (r < SS + MM) {
        const int m = r - SS;
        if (cb < SS) {
            const int4 mt = *(const int4*)(midtgt + b * SS + cb);
            o.x = (mt.x == m) ? 1.f : 0.f;
            o.y = (mt.y == m) ? 1.f : 0.f;
            o.z = (mt.z == m) ? 1.f : 0.f;
            o.w = (mt.w == m) ? 1.f : 0.f;
        } else {
            o.x = (cb == r)     ? 1.f : 0.f;
            o.y = (cb + 1 == r) ? 1.f : 0.f;
            o.z = (cb + 2 == r) ? 1.f : 0.f;
            o.w = (cb + 3 == r) ? 1.f : 0.f;
        }
    } else {
        const int cc = r - SS - MM;
        if (cb < SS) {
            const int4 ct = *(const int4*)(coatgt + b * SS + cb);
            o.x = (ct.x == cc) ? 1.f : 0.f;
            o.y = (ct.y == cc) ? 1.f : 0.f;
            o.z = (ct.z == cc) ? 1.f : 0.f;
            o.w = (ct.w == cc) ? 1.f : 0.f;
        } else {
            o.x = (cb == r)     ? 1.f : 0.f;
            o.y = (cb + 1 == r) ? 1.f : 0.f;
            o.z = (cb + 2 == r) ? 1.f : 0.f;
            o.w = (cb + 3 == r) ? 1.f : 0.f;
        }
    }
    *(float4*)(out + (size_t)rt * TT + cb) = o;
}

// ---------------------------------------------------------------------------
// fmaf-chain 4-wide dot helper (function, not a macro)
// ---------------------------------------------------------------------------
__device__ __forceinline__ float dot4(float acc, const float4& va, const float4& vb)
{
    return fmaf(va.x, vb.x, fmaf(va.y, vb.y, fmaf(va.z, vb.z, fmaf(va.w, vb.w, acc))));
}

// ---------------------------------------------------------------------------
// logits stage 1: proj[b,m,e] = sum_d mid[b,m,d] * W[e,d]
// ---------------------------------------------------------------------------
__global__ __launch_bounds__(256) void proj_kernel(
    const float* __restrict__ mid_hidden, const float* __restrict__ W,
    float* __restrict__ proj)
{
    const int b = blockIdx.z;
    const int m0 = blockIdx.y * 32 + (threadIdx.x >> 4) * 2;
    const int e0 = blockIdx.x * 64 + (threadIdx.x & 15) * 4;
    const float* a0 = mid_hidden + (size_t)(b * MM + m0) * DD;
    const float* a1 = a0 + DD;
    const float* w0 = W + (size_t)e0 * DD;
    const float* w1 = w0 + DD;
    const float* w2 = w1 + DD;
    const float* w3 = w2 + DD;
    float acc[2][4] = {};
    for (int k = 0; k < DD; k += 4) {
        const float4 va0 = *(const float4*)(a0 + k);
        const float4 va1 = *(const float4*)(a1 + k);
        const float4 vw0 = *(const float4*)(w0 + k);
        const float4 vw1 = *(const float4*)(w1 + k);
        const float4 vw2 = *(const float4*)(w2 + k);
        const float4 vw3 = *(const float4*)(w3 + k);
        acc[0][0] = dot4(acc[0][0], va0, vw0); acc[0][1] = dot4(acc[0][1], va0, vw1);
        acc[0][2] = dot4(acc[0][2], va0, vw2); acc[0][3] = dot4(acc[0][3], va0, vw3);
        acc[1][0] = dot4(acc[1][0], va1, vw0); acc[1][1] = dot4(acc[1][1], va1, vw1);
        acc[1][2] = dot4(acc[1][2], va1, vw2); acc[1][3] = dot4(acc[1][3], va1, vw3);
    }
    float* p0 = proj + (size_t)(b * MM + m0) * DD + e0;
    float* p1 = p0 + DD;
    p0[0] = acc[0][0]; p0[1] = acc[0][1]; p0[2] = acc[0][2]; p0[3] = acc[0][3];
    p1[0] = acc[1][0]; p1[1] = acc[1][1]; p1[2] = acc[1][2]; p1[3] = acc[1][3];
}

// ---------------------------------------------------------------------------
// logits stage 2: G[b,m,n] = (mm[m]&mm[n]) ? (proj[m]·proj[n]) / sqrt(D) : 0
// ---------------------------------------------------------------------------
__global__ __launch_bounds__(256) void logits_kernel(
    const float* __restrict__ proj, const int* __restrict__ mid_mask,
    float* __restrict__ out)
{
    const int b = blockIdx.z;
    const int m0 = blockIdx.y * 32 + (threadIdx.x >> 4) * 2;
    const int n0 = blockIdx.x * 32 + (threadIdx.x & 15) * 2;
    const float* pm0 = proj + (size_t)(b * MM + m0) * DD;
    const float* pm1 = pm0 + DD;
    const float* pn0 = proj + (size_t)(b * MM + n0) * DD;
    const float* pn1 = pn0 + DD;
    float acc[2][2] = {};
    for (int k = 0; k < DD; k += 4) {
        const float4 a0 = *(const float4*)(pm0 + k);
        const float4 a1 = *(const float4*)(pm1 + k);
        const float4 q0 = *(const float4*)(pn0 + k);
        const float4 q1 = *(const float4*)(pn1 + k);
        acc[0][0] = dot4(acc[0][0], a0, q0); acc[0][1] = dot4(acc[0][1], a0, q1);
        acc[1][0] = dot4(acc[1][0], a1, q0); acc[1][1] = dot4(acc[1][1], a1, q1);
    }
    const bool qm0 = mid_mask[b * MM + m0] > 0;
    const bool qm1 = mid_mask[b * MM + m0 + 1] > 0;
    const bool qn0 = mid_mask[b * MM + n0] > 0;
    const bool qn1 = mid_mask[b * MM + n0 + 1] > 0;
    const float sc = 22.62741699796952f;  // float32(sqrt(512)); ref divides
    float* o = out + (size_t)(b * MM + m0) * MM + n0;
    o[0]       = (qm0 && qn0) ? acc[0][0] / sc : 0.f;
    o[1]       = (qm0 && qn1) ? acc[0][1] / sc : 0.f;
    o[MM]      = (qm1 && qn0) ? acc[1][0] / sc : 0.f;
    o[MM + 1]  = (qm1 && qn1) ? acc[1][1] / sc : 0.f;
}

// ---------------------------------------------------------------------------
extern "C" void kernel_launch(void* const* d_in, const int* in_sizes, int n_in,
                              void* d_out, int out_size, void* d_ws, size_t ws_size,
                              hipStream_t stream)
{
    const float* coords      = (const float*)d_in[0];
    const int*   tokens      = (const int*)d_in[1];
    const int*   step_mask   = (const int*)d_in[2];
    const int*   s2m         = (const int*)d_in[3];
    const int*   mid_mask    = (const int*)d_in[4];
    const int*   s2c         = (const int*)d_in[5];
    const int*   coarse_mask = (const int*)d_in[6];
    const float* mid_hidden  = (const float*)d_in[7];
    const float* W_flow      = (const float*)d_in[8];

    float* graph_out  = (float*)d_out;
    float* attn_out   = graph_out + (size_t)BB * SS * SS;
    float* logits_out = attn_out + (size_t)BB * TT * TT;

    char* ws = (char*)d_ws;
    u32* colkey  = (u32*)(ws + OFF_COLKEY);
    int* midtgt  = (int*)(ws + OFF_MIDTGT);
    int* coatgt  = (int*)(ws + OFF_COATGT);
    u32* knnbits = (u32*)(ws + OFF_KNN);
    // If ws is tight, alias proj onto knnbits (safe: proj kernels run after
    // graph_kernel has consumed knnbits; stream order serializes).
    float* proj = (ws_size >= OFF_PROJ + PROJ_BYTES) ? (float*)(ws + OFF_PROJ)
                                                     : (float*)knnbits;

    zero_kernel<<<(int)(KNN_BYTES / (256 * 16)), 256, 0, stream>>>((uint4*)knnbits);
    prep_kernel<<<BB, 256, 0, stream>>>(step_mask, tokens, s2m, mid_mask,
                                        s2c, coarse_mask, colkey, midtgt, coatgt);
    // attn first: no knnbits dependency; its L3 write-back drains under knn.
    attn_kernel<<<(BB * TT * (TT / 4)) / 256, 256, 0, stream>>>(colkey, midtgt, coatgt, attn_out);
    knn_kernel<<<(BB * SS) / 4, 256, 0, stream>>>(coords, colkey, knnbits);
    graph_kernel<<<(BB * SS * (SS / 4)) / 256, 256, 0, stream>>>(colkey, knnbits, graph_out);
    proj_kernel<<<dim3(DD / 64, MM / 32, BB), 256, 0, stream>>>(mid_hidden, W_flow, proj);
    logits_kernel<<<dim3(MM / 32, MM / 32, BB), 256, 0, stream>>>(proj, mid_mask, logits_out);
}